// Round 5
// baseline (329.927 us; speedup 1.0000x reference)
//
#include <hip/hip_runtime.h>

#define N_NODES 16384
#define N_EDGES 524288
#define PANEL_I 32     // rows per block
#define CHUNK_J 2048   // 8 waves x 256 j
// D_IN=3, D_HID=16, D_OUT=16

typedef float f32x4 __attribute__((ext_vector_type(4)));

// ---------------- kernel 1: zero the aggregation buffer ----------------
__global__ void zero_agg_kernel(float* __restrict__ agg) {
    int i = blockIdx.x * blockDim.x + threadIdx.x;
    if (i < N_NODES * 3) agg[i] = 0.0f;
}

// ---------------- kernel 2: scatter-add neighbor features ----------------
__global__ void scatter_kernel(const int* __restrict__ eidx,
                               const float* __restrict__ x,
                               float* __restrict__ agg) {
    int e = blockIdx.x * blockDim.x + threadIdx.x;
    if (e >= N_EDGES) return;
    int s = eidx[e];            // src row
    int t = eidx[N_EDGES + e];  // tgt row
    float f0 = x[s * 3 + 0];
    float f1 = x[s * 3 + 1];
    float f2 = x[s * 3 + 2];
    atomicAdd(&agg[t * 3 + 0], f0);
    atomicAdd(&agg[t * 3 + 1], f1);
    atomicAdd(&agg[t * 3 + 2], f2);
}

// ---------------- kernel 3: GIN MLP per node -> h [N,16] ----------------
__global__ void mlp_kernel(const float* __restrict__ x,
                           const float* __restrict__ agg,
                           const float* __restrict__ W1,
                           const float* __restrict__ b1,
                           const float* __restrict__ W2,
                           const float* __restrict__ b2,
                           const float* __restrict__ eps_p,
                           float* __restrict__ h) {
    int n = blockIdx.x * blockDim.x + threadIdx.x;
    if (n >= N_NODES) return;
    float se = 1.0f + eps_p[0];
    float z0 = se * x[n * 3 + 0] + agg[n * 3 + 0];
    float z1 = se * x[n * 3 + 1] + agg[n * 3 + 1];
    float z2 = se * x[n * 3 + 2] + agg[n * 3 + 2];
    float h1[16];
#pragma unroll
    for (int j = 0; j < 16; ++j) {
        float a = b1[j];
        a += z0 * W1[0 * 16 + j];
        a += z1 * W1[1 * 16 + j];
        a += z2 * W1[2 * 16 + j];
        h1[j] = fmaxf(a, 0.0f);
    }
    float4* h4 = (float4*)&h[n * 16];
#pragma unroll
    for (int oq = 0; oq < 4; ++oq) {
        float4 o;
        float* op = (float*)&o;
#pragma unroll
        for (int c = 0; c < 4; ++c) {
            int oo = oq * 4 + c;
            float a = b2[oo];
#pragma unroll
            for (int j = 0; j < 16; ++j) a += h1[j] * W2[j * 16 + oo];
            op[c] = fmaxf(a, 0.0f);
        }
        h4[oq] = o;
    }
}

// ---------------- kernel 4: out[i][j] = dot(h[i], h[j]) ----------------
// Row-panel layout: 512 blocks x 32-row panels. Per j-chunk (2048 cols), the
// block's 8 waves cover 2048 consecutive j of the SAME row -> each row store
// is 8 KB contiguous from the block (vs 1 KB chunks at 64 KB stride before),
// maximizing DRAM page locality of the 1.07 GB write stream.
// hj fragments are loaded straight from global (h is L2-resident, wave load =
// 16 KB contiguous); hi panel is a 2 KB LDS broadcast.
__global__ __launch_bounds__(512) void pairwise_kernel(const float* __restrict__ h,
                                                       float* __restrict__ out) {
    __shared__ float hi[PANEL_I * 16];   // 2 KB
    const int i0 = blockIdx.x * PANEL_I;
    const int tid = threadIdx.x;
    const int wid = tid >> 6;
    const int lane = tid & 63;

    // stage hi panel: 32 rows x 4 f32x4 = 128 f32x4
    if (tid < PANEL_I * 4) {
        ((f32x4*)hi)[tid] = ((const f32x4*)h)[(size_t)i0 * 4 + tid];
    }
    __syncthreads();

    const f32x4* hg = (const f32x4*)h;
    f32x4* out4 = (f32x4*)out;

    for (int c = 0; c < N_NODES / CHUNK_J; ++c) {
        const int jbase = c * CHUNK_J + wid * 256 + lane * 4;  // first of this thread's 4 j

        // load hj: 4 j-rows x 16 floats from global, transpose to k-major f32x4
        f32x4 hj[16];
#pragma unroll
        for (int jj = 0; jj < 4; ++jj) {
            const size_t jb4 = (size_t)(jbase + jj) * 4;
            f32x4 q0 = hg[jb4 + 0];
            f32x4 q1 = hg[jb4 + 1];
            f32x4 q2 = hg[jb4 + 2];
            f32x4 q3 = hg[jb4 + 3];
            hj[0][jj]  = q0.x;  hj[1][jj]  = q0.y;  hj[2][jj]  = q0.z;  hj[3][jj]  = q0.w;
            hj[4][jj]  = q1.x;  hj[5][jj]  = q1.y;  hj[6][jj]  = q1.z;  hj[7][jj]  = q1.w;
            hj[8][jj]  = q2.x;  hj[9][jj]  = q2.y;  hj[10][jj] = q2.z;  hj[11][jj] = q2.w;
            hj[12][jj] = q3.x;  hj[13][jj] = q3.y;  hj[14][jj] = q3.z;  hj[15][jj] = q3.w;
        }

        const size_t ob = (size_t)i0 * (N_NODES / 4) + (size_t)(jbase >> 2);
#pragma unroll 8
        for (int r = 0; r < PANEL_I; ++r) {
            const f32x4* hr = (const f32x4*)&hi[r * 16];
            f32x4 a0 = hr[0], a1 = hr[1], a2 = hr[2], a3 = hr[3];
            f32x4 acc = a0.x * hj[0];
            acc += a0.y * hj[1];
            acc += a0.z * hj[2];
            acc += a0.w * hj[3];
            acc += a1.x * hj[4];
            acc += a1.y * hj[5];
            acc += a1.z * hj[6];
            acc += a1.w * hj[7];
            acc += a2.x * hj[8];
            acc += a2.y * hj[9];
            acc += a2.z * hj[10];
            acc += a2.w * hj[11];
            acc += a3.x * hj[12];
            acc += a3.y * hj[13];
            acc += a3.z * hj[14];
            acc += a3.w * hj[15];
            out4[ob + (size_t)r * (N_NODES / 4)] = acc;
        }
        __syncthreads();  // keep waves converged so row segments stay clustered
    }
}

extern "C" void kernel_launch(void* const* d_in, const int* in_sizes, int n_in,
                              void* d_out, int out_size, void* d_ws, size_t ws_size,
                              hipStream_t stream) {
    const float* node_feats = (const float*)d_in[0];
    const int*   edge_idx   = (const int*)d_in[1];
    const float* W1         = (const float*)d_in[2];
    const float* b1         = (const float*)d_in[3];
    const float* W2         = (const float*)d_in[4];
    const float* b2         = (const float*)d_in[5];
    const float* eps        = (const float*)d_in[6];
    float* out = (float*)d_out;

    // workspace layout: agg [N*3 floats] at 0, h [N*16 floats] at 256 KB
    float* agg = (float*)d_ws;
    float* h   = (float*)((char*)d_ws + 262144);

    zero_agg_kernel<<<(N_NODES * 3 + 255) / 256, 256, 0, stream>>>(agg);
    scatter_kernel<<<N_EDGES / 256, 256, 0, stream>>>(edge_idx, node_feats, agg);
    mlp_kernel<<<N_NODES / 64, 64, 0, stream>>>(node_feats, agg, W1, b1, W2, b2, eps, h);

    pairwise_kernel<<<N_NODES / PANEL_I, 512, 0, stream>>>(h, out);
}

// Round 6
// 284.984 us; speedup vs baseline: 1.1577x; 1.1577x over previous
//
#include <hip/hip_runtime.h>

#define N_NODES 16384
#define N_EDGES 524288
#define TILE_I 128
#define TILE_J 256
// grid = (16384/128) * (16384/256) = 128 * 64 = 8192 blocks, 1-D + swizzle

typedef float f32x4 __attribute__((ext_vector_type(4)));

// ---------------- kernel 1: scatter-add neighbor features ----------------
__global__ void scatter_kernel(const int* __restrict__ eidx,
                               const float* __restrict__ x,
                               float* __restrict__ agg) {
    int e = blockIdx.x * blockDim.x + threadIdx.x;
    if (e >= N_EDGES) return;
    int s = eidx[e];            // src row
    int t = eidx[N_EDGES + e];  // tgt row
    float f0 = x[s * 3 + 0];
    float f1 = x[s * 3 + 1];
    float f2 = x[s * 3 + 2];
    atomicAdd(&agg[t * 3 + 0], f0);
    atomicAdd(&agg[t * 3 + 1], f1);
    atomicAdd(&agg[t * 3 + 2], f2);
}

// ---------------- kernel 2: GIN MLP per node -> h [N,16] ----------------
__global__ void mlp_kernel(const float* __restrict__ x,
                           const float* __restrict__ agg,
                           const float* __restrict__ W1,
                           const float* __restrict__ b1,
                           const float* __restrict__ W2,
                           const float* __restrict__ b2,
                           const float* __restrict__ eps_p,
                           float* __restrict__ h) {
    int n = blockIdx.x * blockDim.x + threadIdx.x;
    if (n >= N_NODES) return;
    float se = 1.0f + eps_p[0];
    float z0 = se * x[n * 3 + 0] + agg[n * 3 + 0];
    float z1 = se * x[n * 3 + 1] + agg[n * 3 + 1];
    float z2 = se * x[n * 3 + 2] + agg[n * 3 + 2];
    float h1[16];
#pragma unroll
    for (int j = 0; j < 16; ++j) {
        float a = b1[j];
        a += z0 * W1[0 * 16 + j];
        a += z1 * W1[1 * 16 + j];
        a += z2 * W1[2 * 16 + j];
        h1[j] = fmaxf(a, 0.0f);
    }
    float4* h4 = (float4*)&h[n * 16];
#pragma unroll
    for (int oq = 0; oq < 4; ++oq) {
        float4 o;
        float* op = (float*)&o;
#pragma unroll
        for (int c = 0; c < 4; ++c) {
            int oo = oq * 4 + c;
            float a = b2[oo];
#pragma unroll
            for (int j = 0; j < 16; ++j) a += h1[j] * W2[j * 16 + oo];
            op[c] = fmaxf(a, 0.0f);
        }
        h4[oq] = o;
    }
}

// ---------------- kernel 3: out[i][j] = dot(h[i], h[j]) ----------------
// R3 structure (best so far): 128x256 tile, 512 threads, stage once, sync
// once, stream 16 NT stores per wave, exit. NEW: bijective XCD swizzle of the
// flat block index so each XCD owns one contiguous 128 MB output stripe ->
// its L2 write-evictions form quasi-sequential HBM streams.
__global__ __launch_bounds__(512) void pairwise_kernel(const float* __restrict__ h,
                                                       float* __restrict__ out) {
    __shared__ float hi[TILE_I * 16];    // 8 KB, row-major
    __shared__ float hjT[16][TILE_J];    // 16 KB, transposed
    // XCD swizzle: launch-id L runs on XCD (L%8) [round-robin dispatch];
    // remap so XCD k gets tiles [k*1024, (k+1)*1024) = a contiguous i-stripe.
    const int flat = blockIdx.x;
    const int swz = (flat & 7) * 1024 + (flat >> 3);   // 8192 % 8 == 0: bijective
    const int i0 = (swz >> 6) * TILE_I;                // 128 i-bands
    const int j0 = (swz & 63) * TILE_J;                // 64 j-tiles
    const int tid = threadIdx.x;

    const float4* h4 = (const float4*)h;
    float4* hi4 = (float4*)hi;
    // hi: 128 rows x 4 float4 = 512 float4, one per thread
    hi4[tid] = h4[(size_t)i0 * 4 + tid];
    // hjT: 256 rows -> transposed, 1024 float4 in two rounds
#pragma unroll
    for (int k = 0; k < 2; ++k) {
        int idx = tid + k * 512;
        float4 w = h4[(size_t)j0 * 4 + idx];
        int row = idx >> 2, q = idx & 3;
        hjT[q * 4 + 0][row] = w.x;
        hjT[q * 4 + 1][row] = w.y;
        hjT[q * 4 + 2][row] = w.z;
        hjT[q * 4 + 3][row] = w.w;
    }
    __syncthreads();

    const int tx = tid & 63;  // 4 consecutive j (float4) per lane; wave = 256 j
    const int ty = tid >> 6;  // 0..7 -> 16 i-rows per thread

    // 4 j-columns of the j-tile, 16 k-slices, in registers (64 VGPR)
    f32x4 hj[16];
#pragma unroll
    for (int k = 0; k < 16; ++k) hj[k] = *(const f32x4*)&hjT[k][tx * 4];

    f32x4* out4 = (f32x4*)out;
    const size_t obase = (size_t)(i0 + ty * 16) * (N_NODES / 4) + (size_t)(j0 >> 2) + tx;

#pragma unroll
    for (int r = 0; r < 16; ++r) {
        const f32x4* hir4 = (const f32x4*)&hi[(ty * 16 + r) * 16];
        f32x4 a0 = hir4[0], a1 = hir4[1], a2 = hir4[2], a3 = hir4[3];
        f32x4 acc = a0.x * hj[0];
        acc += a0.y * hj[1];
        acc += a0.z * hj[2];
        acc += a0.w * hj[3];
        acc += a1.x * hj[4];
        acc += a1.y * hj[5];
        acc += a1.z * hj[6];
        acc += a1.w * hj[7];
        acc += a2.x * hj[8];
        acc += a2.y * hj[9];
        acc += a2.z * hj[10];
        acc += a2.w * hj[11];
        acc += a3.x * hj[12];
        acc += a3.y * hj[13];
        acc += a3.z * hj[14];
        acc += a3.w * hj[15];
        __builtin_nontemporal_store(acc, &out4[obase + (size_t)r * (N_NODES / 4)]);
    }
}

extern "C" void kernel_launch(void* const* d_in, const int* in_sizes, int n_in,
                              void* d_out, int out_size, void* d_ws, size_t ws_size,
                              hipStream_t stream) {
    const float* node_feats = (const float*)d_in[0];
    const int*   edge_idx   = (const int*)d_in[1];
    const float* W1         = (const float*)d_in[2];
    const float* b1         = (const float*)d_in[3];
    const float* W2         = (const float*)d_in[4];
    const float* b2         = (const float*)d_in[5];
    const float* eps        = (const float*)d_in[6];
    float* out = (float*)d_out;

    // workspace layout: agg [N*3 floats] at 0, h [N*16 floats] at 256 KB
    float* agg = (float*)d_ws;
    float* h   = (float*)((char*)d_ws + 262144);

    hipMemsetAsync(agg, 0, N_NODES * 3 * sizeof(float), stream);
    scatter_kernel<<<N_EDGES / 256, 256, 0, stream>>>(edge_idx, node_feats, agg);
    mlp_kernel<<<N_NODES / 256, 256, 0, stream>>>(node_feats, agg, W1, b1, W2, b2, eps, h);

    pairwise_kernel<<<8192, 512, 0, stream>>>(h, out);
}

// Round 7
// 268.958 us; speedup vs baseline: 1.2267x; 1.0596x over previous
//
#include <hip/hip_runtime.h>

#define N_NODES 16384
#define N_EDGES 524288
#define TILE_I 16      // rows per block
#define TILE_J 2048    // 8 waves x 256 j
// grid = (16384/16) * (16384/2048) = 1024 * 8 = 8192 blocks

typedef float f32x4 __attribute__((ext_vector_type(4)));

// ---------------- kernel 1: scatter-add neighbor features ----------------
__global__ void scatter_kernel(const int* __restrict__ eidx,
                               const float* __restrict__ x,
                               float* __restrict__ agg) {
    int e = blockIdx.x * blockDim.x + threadIdx.x;
    if (e >= N_EDGES) return;
    int s = eidx[e];            // src row
    int t = eidx[N_EDGES + e];  // tgt row
    float f0 = x[s * 3 + 0];
    float f1 = x[s * 3 + 1];
    float f2 = x[s * 3 + 2];
    atomicAdd(&agg[t * 3 + 0], f0);
    atomicAdd(&agg[t * 3 + 1], f1);
    atomicAdd(&agg[t * 3 + 2], f2);
}

// ---------------- kernel 2: GIN MLP per node -> h [N,16] ----------------
__global__ void mlp_kernel(const float* __restrict__ x,
                           const float* __restrict__ agg,
                           const float* __restrict__ W1,
                           const float* __restrict__ b1,
                           const float* __restrict__ W2,
                           const float* __restrict__ b2,
                           const float* __restrict__ eps_p,
                           float* __restrict__ h) {
    int n = blockIdx.x * blockDim.x + threadIdx.x;
    if (n >= N_NODES) return;
    float se = 1.0f + eps_p[0];
    float z0 = se * x[n * 3 + 0] + agg[n * 3 + 0];
    float z1 = se * x[n * 3 + 1] + agg[n * 3 + 1];
    float z2 = se * x[n * 3 + 2] + agg[n * 3 + 2];
    float h1[16];
#pragma unroll
    for (int j = 0; j < 16; ++j) {
        float a = b1[j];
        a += z0 * W1[0 * 16 + j];
        a += z1 * W1[1 * 16 + j];
        a += z2 * W1[2 * 16 + j];
        h1[j] = fmaxf(a, 0.0f);
    }
    float4* h4 = (float4*)&h[n * 16];
#pragma unroll
    for (int oq = 0; oq < 4; ++oq) {
        float4 o;
        float* op = (float*)&o;
#pragma unroll
        for (int c = 0; c < 4; ++c) {
            int oo = oq * 4 + c;
            float a = b2[oo];
#pragma unroll
            for (int j = 0; j < 16; ++j) a += h1[j] * W2[j * 16 + oo];
            op[c] = fmaxf(a, 0.0f);
        }
        h4[oq] = o;
    }
}

// ---------------- kernel 3: out[i][j] = dot(h[i], h[j]) ----------------
// R5's write layout with R3's schedule. 16x2048 tile: the block's 8 waves
// cover 2048 consecutive j of the SAME row per r-step -> 8 KB contiguous
// per row, 16 rows x 8 KB block footprint (vs 128 rows x 1 KB in R3).
// Stage once, sync ONCE (R5's per-chunk sync was the regression), stream
// 16 NT stores per thread, exit.
__global__ __launch_bounds__(512) void pairwise_kernel(const float* __restrict__ h,
                                                       float* __restrict__ out) {
    __shared__ float hi[TILE_I * 16];   // 1 KB
    const int i0 = (blockIdx.x >> 3) * TILE_I;
    const int j0 = (blockIdx.x & 7) * TILE_J;
    const int tid = threadIdx.x;
    const int wid = tid >> 6;
    const int lane = tid & 63;

    // stage hi panel: 16 rows x 4 f32x4 = 64 f32x4
    if (tid < TILE_I * 4) {
        ((f32x4*)hi)[tid] = ((const f32x4*)h)[(size_t)i0 * 4 + tid];
    }

    // load hj: this thread's 4 j-rows straight from global (h is L2-resident),
    // transposed to k-major f32x4 in registers (validated in R5).
    const int jbase = j0 + wid * 256 + lane * 4;
    const f32x4* hg = (const f32x4*)h;
    f32x4 hj[16];
#pragma unroll
    for (int jj = 0; jj < 4; ++jj) {
        const size_t jb4 = (size_t)(jbase + jj) * 4;
        f32x4 q0 = hg[jb4 + 0];
        f32x4 q1 = hg[jb4 + 1];
        f32x4 q2 = hg[jb4 + 2];
        f32x4 q3 = hg[jb4 + 3];
        hj[0][jj]  = q0.x;  hj[1][jj]  = q0.y;  hj[2][jj]  = q0.z;  hj[3][jj]  = q0.w;
        hj[4][jj]  = q1.x;  hj[5][jj]  = q1.y;  hj[6][jj]  = q1.z;  hj[7][jj]  = q1.w;
        hj[8][jj]  = q2.x;  hj[9][jj]  = q2.y;  hj[10][jj] = q2.z;  hj[11][jj] = q2.w;
        hj[12][jj] = q3.x;  hj[13][jj] = q3.y;  hj[14][jj] = q3.z;  hj[15][jj] = q3.w;
    }
    __syncthreads();

    f32x4* out4 = (f32x4*)out;
    const size_t obase = (size_t)i0 * (N_NODES / 4) + (size_t)(jbase >> 2);

#pragma unroll
    for (int r = 0; r < TILE_I; ++r) {
        const f32x4* hr = (const f32x4*)&hi[r * 16];
        f32x4 a0 = hr[0], a1 = hr[1], a2 = hr[2], a3 = hr[3];
        f32x4 acc = a0.x * hj[0];
        acc += a0.y * hj[1];
        acc += a0.z * hj[2];
        acc += a0.w * hj[3];
        acc += a1.x * hj[4];
        acc += a1.y * hj[5];
        acc += a1.z * hj[6];
        acc += a1.w * hj[7];
        acc += a2.x * hj[8];
        acc += a2.y * hj[9];
        acc += a2.z * hj[10];
        acc += a2.w * hj[11];
        acc += a3.x * hj[12];
        acc += a3.y * hj[13];
        acc += a3.z * hj[14];
        acc += a3.w * hj[15];
        __builtin_nontemporal_store(acc, &out4[obase + (size_t)r * (N_NODES / 4)]);
    }
}

extern "C" void kernel_launch(void* const* d_in, const int* in_sizes, int n_in,
                              void* d_out, int out_size, void* d_ws, size_t ws_size,
                              hipStream_t stream) {
    const float* node_feats = (const float*)d_in[0];
    const int*   edge_idx   = (const int*)d_in[1];
    const float* W1         = (const float*)d_in[2];
    const float* b1         = (const float*)d_in[3];
    const float* W2         = (const float*)d_in[4];
    const float* b2         = (const float*)d_in[5];
    const float* eps        = (const float*)d_in[6];
    float* out = (float*)d_out;

    // workspace layout: agg [N*3 floats] at 0, h [N*16 floats] at 256 KB
    float* agg = (float*)d_ws;
    float* h   = (float*)((char*)d_ws + 262144);

    hipMemsetAsync(agg, 0, N_NODES * 3 * sizeof(float), stream);
    scatter_kernel<<<N_EDGES / 256, 256, 0, stream>>>(edge_idx, node_feats, agg);
    mlp_kernel<<<N_NODES / 256, 256, 0, stream>>>(node_feats, agg, W1, b1, W2, b2, eps, h);

    pairwise_kernel<<<8192, 512, 0, stream>>>(h, out);
}